// Round 1
// baseline (677.308 us; speedup 1.0000x reference)
//
#include <hip/hip_runtime.h>
#include <cstdint>
#include <cstddef>

#define NH 8
#define NB 4
#define SS 2048
#define FF 64
#define DD 8
#define QKV_SZ (NH*NB*SS*DD)   // 524288 floats = 2 MB

// Full 64-lane sum via DPP (rocPRIM sequence). Result valid in lane 63.
__device__ __forceinline__ float wave_sum64(float x) {
#define DPP_STEP(ctrl, rm) { int t_ = __builtin_amdgcn_update_dpp(0, __float_as_int(x), (ctrl), (rm), 0xf, true); x += __int_as_float(t_); }
  DPP_STEP(0x111, 0xf)  // row_shr:1
  DPP_STEP(0x112, 0xf)  // row_shr:2
  DPP_STEP(0x114, 0xf)  // row_shr:4
  DPP_STEP(0x118, 0xf)  // row_shr:8
  DPP_STEP(0x142, 0xa)  // row_bcast:15 -> rows 1,3
  DPP_STEP(0x143, 0xc)  // row_bcast:31 -> rows 2,3
#undef DPP_STEP
  return x;
}

// ---------------- Kernel A: QKV projection ----------------
// Q is pre-scaled by 1/sqrt(8). Layouts: Q/K/V = [h][b][s][d].
__global__ __launch_bounds__(256) void qkv_kernel(
    const float* __restrict__ x,
    const float* __restrict__ Wq, const float* __restrict__ Wk, const float* __restrict__ Wv,
    float* __restrict__ Qo, float* __restrict__ Ko, float* __restrict__ Vo) {
  __shared__ float xT[64][64];  // [f][r] transposed -> conflict-free lane=r reads
  const int tid = threadIdx.x;
  const int row0 = blockIdx.x * 64;
  // stage 64 rows of x, transposed
  #pragma unroll
  for (int k = 0; k < 4; ++k) {
    int flat4 = tid + 256 * k;          // 0..1023
    int r = flat4 >> 4, fq = flat4 & 15;
    float4 xv = reinterpret_cast<const float4*>(x)[(size_t)(row0 + r) * 16 + fq];
    xT[fq * 4 + 0][r] = xv.x; xT[fq * 4 + 1][r] = xv.y;
    xT[fq * 4 + 2][r] = xv.z; xT[fq * 4 + 3][r] = xv.w;
  }
  __syncthreads();
  const int r = tid & 63;
  const int g = __builtin_amdgcn_readfirstlane(tid >> 6);  // wave-uniform output group
  const int obase = g * 48;
  float acc[48];
  #pragma unroll
  for (int i = 0; i < 48; ++i) acc[i] = 0.f;
  for (int f = 0; f < 64; ++f) {
    float xv = xT[f][r];
    #pragma unroll
    for (int i = 0; i < 48; ++i) {
      int o = obase + i;
      const float* Wsel = (o < 64) ? Wq : ((o < 128) ? Wk : Wv);
      int oc = o & 63;
      // W[h][f][d] flat = h*512 + f*8 + d
      acc[i] = fmaf(xv, Wsel[((oc >> 3) << 9) + f * 8 + (oc & 7)], acc[i]);
    }
  }
  const int row = row0 + r;
  const int b = row >> 11, s = row & 2047;
  const float qscale = 0.35355339059327373f;  // 1/sqrt(8)
  #pragma unroll
  for (int i = 0; i < 48; ++i) {
    int o = obase + i;
    int m = o >> 6, oc = o & 63, h = oc >> 3, d = oc & 7;
    float v = acc[i];
    if (m == 0) v *= qscale;
    float* dst = (m == 0) ? Qo : ((m == 1) ? Ko : Vo);
    dst[(((size_t)(h * NB + b) * SS) + s) * DD + d] = v;
  }
}

// ---------------- Kernel B: softmax weights + head sums ----------------
// Grid: 1024 blocks = 32 (h,b) x 32 row-tiles of 64 rows. 256 threads = 4 waves.
// Phase 1: row sums (K chunks of 256 t in regs, lane=t, rows looped, DPP reduce).
// Phase 2: normalized weights written coalesced + thread-local A[d] head-sum accum.
__global__ __launch_bounds__(256, 4) void attn_kernel(
    const float* __restrict__ Qg, const float* __restrict__ Kg, const float* __restrict__ Vg,
    float* __restrict__ wOut, float* __restrict__ hsum2) {
  __shared__ float psum[64][9];
  __shared__ float rinv_s[64];
  __shared__ float hred[4][8];
  const int tid = threadIdx.x;
  const int lane = tid & 63;
  const int w = tid >> 6;
  const int bx = blockIdx.x;
  const int hb = bx >> 5;   // h*4+b
  const int rt = bx & 31;
  const int r0 = rt * 64;
  const float* Kbase = Kg + (size_t)hb * SS * DD;
  const float* Vbase = Vg + (size_t)hb * SS * DD;
  const float4* Qv = reinterpret_cast<const float4*>(Qg + (size_t)hb * SS * DD + (size_t)r0 * DD);
  float* wBase = wOut + (size_t)hb * SS * SS + (size_t)r0 * SS;

  // ---- Phase 1: row sums. Chunks of 256 t (4 t per lane), 2 chunks per wave. ----
  for (int ci = 0; ci < 2; ++ci) {
    const int c = w * 2 + ci;
    const int tbase = c * 256;
    float Kf[4][8];
    #pragma unroll
    for (int j = 0; j < 4; ++j) {
      const float4* kp = reinterpret_cast<const float4*>(Kbase + (size_t)(tbase + 64 * j + lane) * DD);
      float4 a = kp[0], bv = kp[1];
      Kf[j][0] = a.x;  Kf[j][1] = a.y;  Kf[j][2] = a.z;  Kf[j][3] = a.w;
      Kf[j][4] = bv.x; Kf[j][5] = bv.y; Kf[j][6] = bv.z; Kf[j][7] = bv.w;
    }
    float4 qa = Qv[0], qb = Qv[1];
    for (int r = 0; r < 64; ++r) {
      int rn = (r < 63) ? (r + 1) : 63;
      float4 na = Qv[rn * 2], nb = Qv[rn * 2 + 1];  // prefetch next row
      float q[8] = {qa.x, qa.y, qa.z, qa.w, qb.x, qb.y, qb.z, qb.w};
      float part = 0.f;
      #pragma unroll
      for (int j = 0; j < 4; ++j) {
        float sc = 0.f;
        #pragma unroll
        for (int d = 0; d < 8; ++d) sc = fmaf(q[d], Kf[j][d], sc);
        part += __expf(sc);
      }
      float tot = wave_sum64(part);
      if (lane == 63) psum[r][c] = tot;
      qa = na; qb = nb;
    }
  }
  __syncthreads();
  if (tid < 64) {
    float ssum = 0.f;
    #pragma unroll
    for (int k = 0; k < 8; ++k) ssum += psum[tid][k];
    rinv_s[tid] = 1.0f / ssum;
  }
  __syncthreads();

  // ---- Phase 2: write weights + accumulate head sums. Chunks of 128 t, 4 per wave. ----
  float A[8] = {0.f, 0.f, 0.f, 0.f, 0.f, 0.f, 0.f, 0.f};
  for (int ci = 0; ci < 4; ++ci) {
    const int c = w * 4 + ci;          // 0..15
    const int tbase = c * 128;
    float Kf[2][8], Vf[2][8];
    #pragma unroll
    for (int j = 0; j < 2; ++j) {
      const float4* kp = reinterpret_cast<const float4*>(Kbase + (size_t)(tbase + 64 * j + lane) * DD);
      float4 a = kp[0], bv = kp[1];
      Kf[j][0] = a.x;  Kf[j][1] = a.y;  Kf[j][2] = a.z;  Kf[j][3] = a.w;
      Kf[j][4] = bv.x; Kf[j][5] = bv.y; Kf[j][6] = bv.z; Kf[j][7] = bv.w;
      const float4* vp = reinterpret_cast<const float4*>(Vbase + (size_t)(tbase + 64 * j + lane) * DD);
      float4 va = vp[0], vb = vp[1];
      Vf[j][0] = va.x; Vf[j][1] = va.y; Vf[j][2] = va.z; Vf[j][3] = va.w;
      Vf[j][4] = vb.x; Vf[j][5] = vb.y; Vf[j][6] = vb.z; Vf[j][7] = vb.w;
    }
    float4 qa = Qv[0], qb = Qv[1];
    for (int r = 0; r < 64; ++r) {
      int rn = (r < 63) ? (r + 1) : 63;
      float4 na = Qv[rn * 2], nb = Qv[rn * 2 + 1];
      float q[8] = {qa.x, qa.y, qa.z, qa.w, qb.x, qb.y, qb.z, qb.w};
      float rin = rinv_s[r];
      float p[2];
      #pragma unroll
      for (int j = 0; j < 2; ++j) {
        float sc = 0.f;
        #pragma unroll
        for (int d = 0; d < 8; ++d) sc = fmaf(q[d], Kf[j][d], sc);
        p[j] = __expf(sc) * rin;
      }
      float* wr = wBase + (size_t)r * SS + tbase + lane;
      wr[0] = p[0];
      wr[64] = p[1];
      #pragma unroll
      for (int j = 0; j < 2; ++j)
        #pragma unroll
        for (int d = 0; d < 8; ++d) A[d] = fmaf(p[j], Vf[j][d], A[d]);
      qa = na; qb = nb;
    }
  }

  // block-level reduce of A[d] -> hsum2[bx][d]
  #pragma unroll
  for (int d = 0; d < 8; ++d) {
    float t = wave_sum64(A[d]);
    if (lane == 63) hred[w][d] = t;
  }
  __syncthreads();
  if (tid < 8) {
    float t = hred[0][tid] + hred[1][tid] + hred[2][tid] + hred[3][tid];
    hsum2[(size_t)bx * 8 + tid] = t;
  }
}

// ---------------- Kernel C: combine head sums + output projection ----------------
__global__ __launch_bounds__(256) void out_kernel(
    const float* __restrict__ hsum2, const float* __restrict__ Wo,
    float* __restrict__ out) {
  __shared__ float ch[256];  // [hb][d] = [h*4+b]*8 + d
  const int tid = threadIdx.x;
  {
    int hb = tid >> 3, d = tid & 7;
    float s = 0.f;
    for (int rtile = 0; rtile < 32; ++rtile) s += hsum2[(size_t)(hb * 32 + rtile) * 8 + d];
    ch[tid] = s;
  }
  __syncthreads();
  const int b = tid >> 6, f = tid & 63;
  float acc = 0.f;
  for (int h = 0; h < 8; ++h) {
    #pragma unroll
    for (int d = 0; d < 8; ++d) {
      // concat[b][h*8+d] @ Wo[h*8+d][f]
      acc = fmaf(ch[(h * 4 + b) * 8 + d], Wo[(h * 8 + d) * 64 + f], acc);
    }
  }
  out[b * 64 + f] = acc;
}

extern "C" void kernel_launch(void* const* d_in, const int* in_sizes, int n_in,
                              void* d_out, int out_size, void* d_ws, size_t ws_size,
                              hipStream_t stream) {
  const float* x  = (const float*)d_in[0];
  const float* Wq = (const float*)d_in[1];
  const float* Wk = (const float*)d_in[2];
  const float* Wv = (const float*)d_in[3];
  const float* Wo = (const float*)d_in[4];
  float* out = (float*)d_out;           // [4,64] = 256 floats
  float* wts = out + 256;               // weights [8,4,2048,2048]
  float* ws = (float*)d_ws;
  float* Q = ws;
  float* K = ws + QKV_SZ;
  float* V = ws + 2 * (size_t)QKV_SZ;
  float* hs = ws + 3 * (size_t)QKV_SZ;  // [1024][8]

  qkv_kernel<<<128, 256, 0, stream>>>(x, Wq, Wk, Wv, Q, K, V);
  attn_kernel<<<1024, 256, 0, stream>>>(Q, K, V, wts, hs);
  out_kernel<<<1, 256, 0, stream>>>(hs, Wo, out);
}